// Round 1
// baseline (383.466 us; speedup 1.0000x reference)
//
#include <hip/hip_runtime.h>
#include <math.h>

#define Bb 64
#define Dd 4096
#define Hh 32
#define Kk 128
#define Vv 128
#define Mm 4096
#define MC 4097

// workspace layout (float offsets)
#define WS_Q      0
#define WS_NEWK   (WS_Q + Bb*Hh*Kk)        // 262144
#define WS_NEWV   (WS_NEWK + Bb*Kk)        // 270336
#define WS_LOGITS (WS_NEWV + Bb*Vv)        // 278528
#define WS_SMAX   (WS_LOGITS + Bb*Hh*MC)   // 8669184
#define WS_SSUM   (WS_SMAX + Bb*Hh)        // 8671232
#define WS_O      (WS_SSUM + Bb*Hh)        // 8673280

// d_out layout (float offsets): y, Kc, Vc
#define OUT_Y  0
#define OUT_KC (Bb*Dd)                      // 262144
#define OUT_VC (OUT_KC + Bb*MC*Kk)          // 33824768

// ---------------- K1: q = x @ P_q (per head), new_k = x @ P_k, new_v = x @ P_v
// grid (34, 16): x = head index (32,33 => P_k,P_v), y = d-chunk of 256
__global__ __launch_bounds__(256) void k1_proj(const float* __restrict__ x,
        const float* __restrict__ Pq, const float* __restrict__ Pk,
        const float* __restrict__ Pv, float* __restrict__ ws) {
    const int hidx = blockIdx.x;
    const int d0c  = blockIdx.y * 256;
    const int t = threadIdx.x;
    const int kg = t & 15, bg = t >> 4;
    const int k0 = kg * 8, b0 = bg * 4;

    const bool isq = (hidx < Hh);
    const float* P;
    float* out;
    if (isq)            { P = Pq + (size_t)hidx * Dd * Kk; out = ws + WS_Q; }
    else if (hidx == Hh){ P = Pk;                          out = ws + WS_NEWK; }
    else                { P = Pv;                          out = ws + WS_NEWV; }

    __shared__ float xs[32][68];       // [d-sub][b], padded
    __shared__ float ps[32 * 128];     // [d-sub][k]

    float acc[4][8];
    #pragma unroll
    for (int a = 0; a < 4; a++)
        #pragma unroll
        for (int c = 0; c < 8; c++) acc[a][c] = 0.f;

    for (int tt = 0; tt < 8; tt++) {
        const int d0 = d0c + tt * 32;
        #pragma unroll
        for (int ii = 0; ii < 8; ii++) {   // xs: 2048 scalars
            int f = ii * 256 + t;
            int bb = f >> 5, i = f & 31;
            xs[i][bb] = x[(size_t)bb * Dd + d0 + i];
        }
        #pragma unroll
        for (int ii = 0; ii < 4; ii++) {   // ps: 1024 float4
            int f = ii * 256 + t;
            int i = f >> 5, k4 = (f & 31) * 4;
            *(float4*)&ps[i * 128 + k4] = *(const float4*)&P[(size_t)(d0 + i) * Kk + k4];
        }
        __syncthreads();
        #pragma unroll
        for (int i = 0; i < 32; i++) {
            float4 xv = *(float4*)&xs[i][b0];
            float4 p0 = *(float4*)&ps[i * 128 + k0];
            float4 p1 = *(float4*)&ps[i * 128 + k0 + 4];
            float xb[4] = {xv.x, xv.y, xv.z, xv.w};
            float pp[8] = {p0.x, p0.y, p0.z, p0.w, p1.x, p1.y, p1.z, p1.w};
            #pragma unroll
            for (int a = 0; a < 4; a++)
                #pragma unroll
                for (int c = 0; c < 8; c++)
                    acc[a][c] = fmaf(xb[a], pp[c], acc[a][c]);
        }
        __syncthreads();
    }
    #pragma unroll
    for (int a = 0; a < 4; a++) {
        int b = b0 + a;
        #pragma unroll
        for (int c = 0; c < 8; c++) {
            int k = k0 + c;
            size_t idx = isq ? ((size_t)(b * Hh + hidx) * Kk + k)
                             : ((size_t)b * Kk + k);
            atomicAdd(&out[idx], acc[a][c]);
        }
    }
}

// ---------------- K2: copy prev_K -> Kc, fused logits[b,h,m] = q[b,h,:].Kc[b,m,:]
// grid (64 m-tiles, 64 b), tile = 64 m
__global__ __launch_bounds__(256) void k2_kcopy_logits(const float* __restrict__ prevK,
        const float* __restrict__ wq, float* __restrict__ outKc,
        float* __restrict__ logits) {
    const int m0 = blockIdx.x * 64;
    const int b  = blockIdx.y;
    const int t  = threadIdx.x;
    __shared__ float qs[128 * 36];   // [k][h], padded
    __shared__ float ks[128 * 66];   // [k][m], padded

    #pragma unroll
    for (int ii = 0; ii < 16; ii++) {     // qs transpose-stage (scalar)
        int f = ii * 256 + t;
        int h = f >> 7, k = f & 127;
        qs[k * 36 + h] = wq[(size_t)(b * Hh + h) * Kk + k];
    }
    #pragma unroll
    for (int ii = 0; ii < 8; ii++) {      // ks stage (float4) + Kc copy
        int f = ii * 256 + t;
        int mm = f >> 5, k4 = (f & 31) * 4;
        size_t src = ((size_t)b * Mm + (m0 + mm)) * Kk + k4;
        float4 v = *(const float4*)&prevK[src];
        *(float4*)&outKc[((size_t)b * MC + (m0 + mm)) * Kk + k4] = v;
        ks[(k4 + 0) * 66 + mm] = v.x;
        ks[(k4 + 1) * 66 + mm] = v.y;
        ks[(k4 + 2) * 66 + mm] = v.z;
        ks[(k4 + 3) * 66 + mm] = v.w;
    }
    __syncthreads();
    const int mg = t & 31, hg = t >> 5;
    const int h0 = hg * 4, mA = mg * 2;
    float acc[4][2] = {};
    for (int k = 0; k < 128; k++) {
        float4 qv = *(float4*)&qs[k * 36 + h0];
        float2 kv = *(float2*)&ks[k * 66 + mA];
        float qa[4] = {qv.x, qv.y, qv.z, qv.w};
        #pragma unroll
        for (int a = 0; a < 4; a++) {
            acc[a][0] = fmaf(qa[a], kv.x, acc[a][0]);
            acc[a][1] = fmaf(qa[a], kv.y, acc[a][1]);
        }
    }
    #pragma unroll
    for (int a = 0; a < 4; a++)
        #pragma unroll
        for (int j = 0; j < 2; j++)
            logits[(size_t)(b * Hh + h0 + a) * MC + m0 + mA + j] = acc[a][j];
}

// ---------------- K2b: Kc[:,M,:] = new_k ; logits[:, :, M] = q . new_k
__global__ __launch_bounds__(256) void k2b_newrow_logits(const float* __restrict__ ws,
        float* __restrict__ outKc) {
    const int b = blockIdx.x, t = threadIdx.x;
    const float* newk = ws + WS_NEWK;
    const float* q    = ws + WS_Q;
    float* logits = (float*)(ws + WS_LOGITS);
    if (t < 128) outKc[((size_t)b * MC + Mm) * Kk + t] = newk[b * Kk + t];
    int h = t >> 3, j = t & 7;
    float s = 0.f;
    #pragma unroll
    for (int c = 0; c < 16; c++) {
        int k = j + c * 8;
        s += q[(size_t)(b * Hh + h) * Kk + k] * newk[b * Kk + k];
    }
    s += __shfl_xor(s, 1, 64);
    s += __shfl_xor(s, 2, 64);
    s += __shfl_xor(s, 4, 64);
    if (j == 0) logits[(size_t)(b * Hh + h) * MC + Mm] = s;
}

// ---------------- K3: per (b,h) row: max and sum(exp(l - max))
__global__ __launch_bounds__(256) void k3_stats(const float* __restrict__ logits,
        float* __restrict__ smax, float* __restrict__ ssum) {
    const int bh = blockIdx.x, t = threadIdx.x;
    const float* row = logits + (size_t)bh * MC;
    float v[17];
    #pragma unroll
    for (int i = 0; i < 17; i++) {
        int idx = i * 256 + t;
        v[i] = (idx < MC) ? row[idx] : -3.0e38f;
    }
    float m = v[0];
    #pragma unroll
    for (int i = 1; i < 17; i++) m = fmaxf(m, v[i]);
    #pragma unroll
    for (int off = 32; off; off >>= 1) m = fmaxf(m, __shfl_xor(m, off, 64));
    __shared__ float red[4];
    if ((t & 63) == 0) red[t >> 6] = m;
    __syncthreads();
    m = fmaxf(fmaxf(red[0], red[1]), fmaxf(red[2], red[3]));
    float s = 0.f;
    #pragma unroll
    for (int i = 0; i < 17; i++) s += __expf(v[i] - m);
    #pragma unroll
    for (int off = 32; off; off >>= 1) s += __shfl_xor(s, off, 64);
    __syncthreads();
    if ((t & 63) == 0) red[t >> 6] = s;
    __syncthreads();
    if (t == 0) {
        smax[bh] = m;
        ssum[bh] = red[0] + red[1] + red[2] + red[3];
    }
}

// ---------------- K4: copy prev_V -> Vc, fused partial O += w * Vc
// grid (16 m-supertiles of 256, 64 b)
__global__ __launch_bounds__(256) void k4_vcopy_pv(const float* __restrict__ prevV,
        const float* __restrict__ logits, const float* __restrict__ smax,
        const float* __restrict__ ssum, float* __restrict__ outVc,
        float* __restrict__ O) {
    const int mbase = blockIdx.x * 256;
    const int b = blockIdx.y;
    const int t = threadIdx.x;
    __shared__ float vs[64 * 128];   // [m][v]
    __shared__ float wl[64 * 36];    // [m][h], padded
    __shared__ float mxs[32], rss[32];
    if (t < 32) { mxs[t] = smax[b * Hh + t]; rss[t] = 1.f / ssum[b * Hh + t]; }
    __syncthreads();
    const int vg = t & 31, hg = t >> 5;
    const int v0 = vg * 4, h0 = hg * 4;
    float acc[4][4] = {};   // [h][v]
    for (int st = 0; st < 4; st++) {
        const int m0 = mbase + st * 64;
        #pragma unroll
        for (int ii = 0; ii < 8; ii++) {   // V stage (float4) + Vc copy
            int f = ii * 256 + t;
            int mm = f >> 5, v4 = (f & 31) * 4;
            float4 vv = *(const float4*)&prevV[((size_t)b * Mm + m0 + mm) * Vv + v4];
            *(float4*)&outVc[((size_t)b * MC + m0 + mm) * Vv + v4] = vv;
            *(float4*)&vs[mm * 128 + v4] = vv;
        }
        #pragma unroll
        for (int ii = 0; ii < 8; ii++) {   // weights stage
            int f = ii * 256 + t;
            int h = f >> 6, mm = f & 63;
            float l = logits[(size_t)(b * Hh + h) * MC + m0 + mm];
            wl[mm * 36 + h] = __expf(l - mxs[h]) * rss[h];
        }
        __syncthreads();
        for (int mm = 0; mm < 64; mm++) {
            float4 vv = *(float4*)&vs[mm * 128 + v0];
            float4 wv = *(float4*)&wl[mm * 36 + h0];
            float va[4] = {vv.x, vv.y, vv.z, vv.w};
            float wa[4] = {wv.x, wv.y, wv.z, wv.w};
            #pragma unroll
            for (int a = 0; a < 4; a++)
                #pragma unroll
                for (int c = 0; c < 4; c++)
                    acc[a][c] = fmaf(wa[a], va[c], acc[a][c]);
        }
        __syncthreads();
    }
    #pragma unroll
    for (int a = 0; a < 4; a++)
        #pragma unroll
        for (int c = 0; c < 4; c++)
            atomicAdd(&O[(size_t)(b * Hh + h0 + a) * Vv + v0 + c], acc[a][c]);
}

// ---------------- K4b: Vc[:,M,:] = new_v ; O += w[:, :, M] * new_v
__global__ __launch_bounds__(256) void k4b_newrow_pv(const float* __restrict__ ws,
        float* __restrict__ outVc, float* __restrict__ O) {
    const int b = blockIdx.x, t = threadIdx.x;
    const float* newv   = ws + WS_NEWV;
    const float* logits = ws + WS_LOGITS;
    const float* smax   = ws + WS_SMAX;
    const float* ssum   = ws + WS_SSUM;
    __shared__ float wm[32];
    if (t < 32) {
        float l = logits[(size_t)(b * Hh + t) * MC + Mm];
        wm[t] = __expf(l - smax[b * Hh + t]) / ssum[b * Hh + t];
    }
    __syncthreads();
    int v = t & 127, hg = t >> 7;
    float nv = newv[b * Vv + v];
    if (t < 128) outVc[((size_t)b * MC + Mm) * Vv + v] = nv;
    #pragma unroll
    for (int hh = 0; hh < 16; hh++) {
        int h = hg * 16 + hh;
        atomicAdd(&O[(size_t)(b * Hh + h) * Vv + v], wm[h] * nv);
    }
}

// ---------------- K5: y[b,d] = sum_{h,v} O[b,h,v] * P_o[h,d,v]
// grid (64 d-tiles of 64, 4 h-quads of 8)
__global__ __launch_bounds__(256) void k5_outproj(const float* __restrict__ O,
        const float* __restrict__ Po, float* __restrict__ y) {
    const int dbase = blockIdx.x * 64;
    const int hq = blockIdx.y;
    const int t = threadIdx.x;
    __shared__ float ps2[128 * 66];  // [v][d], padded
    __shared__ float os2[128 * 66];  // [v][b], padded
    const int dg = t & 15, bg = t >> 4;
    const int dd0 = dg * 4, b0 = bg * 4;
    float acc[4][4] = {};   // [b][d]
    for (int hi = 0; hi < 8; hi++) {
        const int h = hq * 8 + hi;
        #pragma unroll
        for (int ii = 0; ii < 8; ii++) {
            int f = ii * 256 + t;
            int r = f >> 5, v4 = (f & 31) * 4;    // r doubles as dd (Po) and bb (O)
            float4 pv = *(const float4*)&Po[((size_t)h * Dd + dbase + r) * Vv + v4];
            ps2[(v4 + 0) * 66 + r] = pv.x;
            ps2[(v4 + 1) * 66 + r] = pv.y;
            ps2[(v4 + 2) * 66 + r] = pv.z;
            ps2[(v4 + 3) * 66 + r] = pv.w;
            float4 ov = *(const float4*)&O[((size_t)r * Hh + h) * Vv + v4];
            os2[(v4 + 0) * 66 + r] = ov.x;
            os2[(v4 + 1) * 66 + r] = ov.y;
            os2[(v4 + 2) * 66 + r] = ov.z;
            os2[(v4 + 3) * 66 + r] = ov.w;
        }
        __syncthreads();
        for (int v = 0; v < 128; v++) {
            float2 pa = *(float2*)&ps2[v * 66 + dd0];
            float2 pb = *(float2*)&ps2[v * 66 + dd0 + 2];
            float2 oa = *(float2*)&os2[v * 66 + b0];
            float2 ob = *(float2*)&os2[v * 66 + b0 + 2];
            float pd[4]  = {pa.x, pa.y, pb.x, pb.y};
            float ob4[4] = {oa.x, oa.y, ob.x, ob.y};
            #pragma unroll
            for (int a = 0; a < 4; a++)
                #pragma unroll
                for (int c = 0; c < 4; c++)
                    acc[a][c] = fmaf(ob4[a], pd[c], acc[a][c]);
        }
        __syncthreads();
    }
    #pragma unroll
    for (int a = 0; a < 4; a++)
        #pragma unroll
        for (int c = 0; c < 4; c++)
            atomicAdd(&y[(size_t)(b0 + a) * Dd + dbase + dd0 + c], acc[a][c]);
}

extern "C" void kernel_launch(void* const* d_in, const int* in_sizes, int n_in,
                              void* d_out, int out_size, void* d_ws, size_t ws_size,
                              hipStream_t stream) {
    const float* x     = (const float*)d_in[0];
    const float* prevK = (const float*)d_in[1];
    const float* prevV = (const float*)d_in[2];
    const float* Pq    = (const float*)d_in[3];
    const float* Pk    = (const float*)d_in[4];
    const float* Pv    = (const float*)d_in[5];
    const float* Po    = (const float*)d_in[6];
    float* out = (float*)d_out;
    float* ws  = (float*)d_ws;

    // zero the atomically-accumulated buffers (q/new_k/new_v, O, y)
    hipMemsetAsync(ws + WS_Q, 0, (size_t)(WS_LOGITS - WS_Q) * sizeof(float), stream);
    hipMemsetAsync(ws + WS_O, 0, (size_t)(Bb * Hh * Vv) * sizeof(float), stream);
    hipMemsetAsync(out + OUT_Y, 0, (size_t)(Bb * Dd) * sizeof(float), stream);

    k1_proj<<<dim3(Hh + 2, 16), 256, 0, stream>>>(x, Pq, Pk, Pv, ws);
    k2_kcopy_logits<<<dim3(64, Bb), 256, 0, stream>>>(prevK, ws + WS_Q,
                                                      out + OUT_KC, ws + WS_LOGITS);
    k2b_newrow_logits<<<Bb, 256, 0, stream>>>(ws, out + OUT_KC);
    k3_stats<<<Bb * Hh, 256, 0, stream>>>(ws + WS_LOGITS, ws + WS_SMAX, ws + WS_SSUM);
    k4_vcopy_pv<<<dim3(16, Bb), 256, 0, stream>>>(prevV, ws + WS_LOGITS, ws + WS_SMAX,
                                                  ws + WS_SSUM, out + OUT_VC, ws + WS_O);
    k4b_newrow_pv<<<Bb, 256, 0, stream>>>(ws, out + OUT_VC, ws + WS_O);
    k5_outproj<<<dim3(64, 4), 256, 0, stream>>>(ws + WS_O, Po, out + OUT_Y);
}